// Round 1
// baseline (116.788 us; speedup 1.0000x reference)
//
#include <hip/hip_runtime.h>

#define D_K 576
#define LBDA_INV 2.0f    // 1/lbda, lbda=0.5
#define HALF_LBDA 0.5f
#define EPS 0.01f
#define LDA 40           // BK(32) + 8 shorts pad
#define DSTRIDE 136      // 128 + 8 bf16 pad

typedef __attribute__((ext_vector_type(8))) short short8;
typedef __attribute__((ext_vector_type(4))) short short4v;
typedef __attribute__((ext_vector_type(4))) float f32x4;

__device__ inline short f2bf(float f) {
    unsigned u = __float_as_uint(f);
    u += 0x7FFF + ((u >> 16) & 1);   // round-to-nearest-even
    return (short)(u >> 16);
}
__device__ inline float bf2f(unsigned short s) {
    return __uint_as_float(((unsigned)s) << 16);
}

// ---------------- norms: one wave per 576-elem row ----------------
__global__ __launch_bounds__(256) void norms_kernel(
        const float* __restrict__ sup, const float* __restrict__ qry,
        float* __restrict__ qn, float* __restrict__ sn) {
    int t = threadIdx.x;
    int row = blockIdx.x * 4 + (t >> 6);
    int lane = t & 63;
    const float* base = (row < 16384) ? (qry + (size_t)row * D_K)
                                      : (sup + (size_t)(row - 16384) * D_K);
    float s = 0.f;
#pragma unroll
    for (int i = 0; i < 9; ++i) {
        float v = base[lane + i * 64];
        s += v * v;
    }
#pragma unroll
    for (int off = 32; off > 0; off >>= 1)
        s += __shfl_down(s, off);
    if (lane == 0) {
        float r = sqrtf(s);
        if (row < 16384) qn[row] = r;
        else sn[row - 16384] = r;
    }
}

// ---------------- soft-min helpers (lbda = 0.5) ----------------
__device__ inline float softmin3(float a, float b, float c) {
    float mn = fminf(a, fminf(b, c));
    float s = __expf(-LBDA_INV * (a - mn)) + __expf(-LBDA_INV * (b - mn)) +
              __expf(-LBDA_INV * (c - mn));
    return mn - HALF_LBDA * __logf(s);
}
__device__ inline float softmin2(float a, float b) {
    float mn = fminf(a, b);
    float s = __expf(-LBDA_INV * (a - mn)) + __expf(-LBDA_INV * (b - mn));
    return mn - HALF_LBDA * __logf(s);
}

// OTAM DP over an 8x8 dist tile; element (l,s) at d[l*RS + s*CS].
// W = 10 (pad cols 0 and 9 with d=0). Returns cum[7][9].
template <int RS, int CS>
__device__ float otam_dp(const float* d) {
    float prev[10], cur[10];
    prev[0] = 0.f;
#pragma unroll
    for (int m = 1; m <= 8; ++m) prev[m] = prev[m - 1] + d[0 * RS + (m - 1) * CS];
    prev[9] = prev[8];  // pad col, d=0
#pragma unroll
    for (int l = 1; l < 8; ++l) {
        cur[0] = 0.f;
        // m=1: up-term allowed. terms: diag=prev[0], left=cur[0]=0, up=prev[1]
        cur[1] = d[l * RS + 0 * CS] + softmin3(prev[0], 0.f, prev[1]);
#pragma unroll
        for (int m = 2; m <= 8; ++m)
            cur[m] = d[l * RS + (m - 1) * CS] + softmin2(prev[m - 1], cur[m - 1]);
        // m=9: pad col (d=0), up-term allowed
        cur[9] = softmin3(prev[8], cur[8], prev[9]);
#pragma unroll
        for (int m = 0; m < 10; ++m) prev[m] = cur[m];
    }
    return prev[9];
}

// ---------------- fused: 128x128 frame-dist tile (MFMA) + 256 DPs ----------------
__global__ __launch_bounds__(256, 2) void fused_kernel(
        const float* __restrict__ sup, const float* __restrict__ qry,
        const float* __restrict__ qn, const float* __restrict__ sn,
        float* __restrict__ out) {
    __shared__ short As[128 * LDA];
    __shared__ short Bs[128 * LDA];
    __shared__ unsigned short Ds[128 * DSTRIDE];

    const int t = threadIdx.x;
    const int sblk = blockIdx.x;   // 0..3
    const int qblk = blockIdx.y;   // 0..127

    const float* Ag = qry + (size_t)qblk * 128 * D_K;
    const float* Bg = sup + (size_t)sblk * 128 * D_K;

    const int lane = t & 63;
    const int wave = t >> 6;
    const int wm = wave >> 1, wn = wave & 1;
    const int col16 = lane & 15, quad = lane >> 4;

    f32x4 acc[4][4];
#pragma unroll
    for (int i = 0; i < 4; ++i)
#pragma unroll
        for (int j = 0; j < 4; ++j) acc[i][j] = (f32x4){0.f, 0.f, 0.f, 0.f};

    for (int k0 = 0; k0 < D_K; k0 += 32) {
        __syncthreads();
        // stage 128x32 of A and B, f32 -> bf16
#pragma unroll
        for (int i = 0; i < 4; ++i) {
            int idx = t + i * 256;     // 0..1023
            int r = idx >> 3, c = idx & 7;
            const float4 va = *(const float4*)(Ag + (size_t)r * D_K + k0 + c * 4);
            short4v sa = {f2bf(va.x), f2bf(va.y), f2bf(va.z), f2bf(va.w)};
            *(short4v*)(&As[r * LDA + c * 4]) = sa;
            const float4 vb = *(const float4*)(Bg + (size_t)r * D_K + k0 + c * 4);
            short4v sb = {f2bf(vb.x), f2bf(vb.y), f2bf(vb.z), f2bf(vb.w)};
            *(short4v*)(&Bs[r * LDA + c * 4]) = sb;
        }
        __syncthreads();

        short8 af[4], bf[4];
#pragma unroll
        for (int mt = 0; mt < 4; ++mt)
            af[mt] = *(const short8*)(&As[(wm * 64 + mt * 16 + col16) * LDA + quad * 8]);
#pragma unroll
        for (int nt = 0; nt < 4; ++nt)
            bf[nt] = *(const short8*)(&Bs[(wn * 64 + nt * 16 + col16) * LDA + quad * 8]);
#pragma unroll
        for (int mt = 0; mt < 4; ++mt)
#pragma unroll
            for (int nt = 0; nt < 4; ++nt)
                acc[mt][nt] = __builtin_amdgcn_mfma_f32_16x16x32_bf16(
                    af[mt], bf[nt], acc[mt][nt], 0, 0, 0);
    }

    // epilogue: num -> dist = 1 - num/(|q||s|+eps), park in LDS (bf16)
    // C/D layout: col = lane&15, row = quad*4 + reg
#pragma unroll
    for (int mt = 0; mt < 4; ++mt) {
#pragma unroll
        for (int reg = 0; reg < 4; ++reg) {
            int m = wm * 64 + mt * 16 + quad * 4 + reg;
            float qv = qn[qblk * 128 + m];
#pragma unroll
            for (int nt = 0; nt < 4; ++nt) {
                int n = wn * 64 + nt * 16 + col16;
                float sv = sn[sblk * 128 + n];
                float dist = 1.f - acc[mt][nt][reg] / (qv * sv + EPS);
                Ds[m * DSTRIDE + n] = (unsigned short)f2bf(dist);
            }
        }
    }
    __syncthreads();

    // DP phase: thread t owns pair (ql, sl); 8x8 tile of dists to registers
    const int ql = t >> 4, sl = t & 15;
    float d[64];
#pragma unroll
    for (int l = 0; l < 8; ++l) {
        short8 rowv = *(const short8*)(&Ds[(ql * 8 + l) * DSTRIDE + sl * 8]);
#pragma unroll
        for (int j = 0; j < 8; ++j) d[l * 8 + j] = bf2f((unsigned short)rowv[j]);
    }
    float r1 = otam_dp<8, 1>(d);   // dists
    float r2 = otam_dp<1, 8>(d);   // dists^T
    int qg = qblk * 16 + ql, sg = sblk * 16 + sl;
    out[qg * 64 + sg] = -(r1 + r2);
}

extern "C" void kernel_launch(void* const* d_in, const int* in_sizes, int n_in,
                              void* d_out, int out_size, void* d_ws, size_t ws_size,
                              hipStream_t stream) {
    const float* sup = (const float*)d_in[0];   // [64, 8, 576]
    const float* qry = (const float*)d_in[1];   // [2048, 8, 576]
    float* out = (float*)d_out;                 // [2048, 64]
    float* qn = (float*)d_ws;                   // 16384 f32
    float* sn = qn + 16384;                     // 512 f32

    norms_kernel<<<dim3((16384 + 512) / 4), dim3(256), 0, stream>>>(sup, qry, qn, sn);
    fused_kernel<<<dim3(4, 128), dim3(256), 0, stream>>>(sup, qry, qn, sn, out);
}